// Round 1
// baseline (388.953 us; speedup 1.0000x reference)
//
#include <hip/hip_runtime.h>
#include <hip/hip_bf16.h>
#include <math.h>

#define DTOK 20

// d_ws layout (float offsets). Prepped once per launch by prep_kernel.
//  A_l  [i][j] : x-in, 20-out merged (Wv^T + Wres) matrix, row-major over input i
//  B_l  [j][i] : W1^T (input j contiguous-out i)
//  C1   [j][i] : W2(layer0)^T
//  D1   [j][i] : W3(layer0)^T
//  M2   [j][c] : Wc @ W2(layer1)  folded classifier (20x3)
//  M3   [j][c] : Wc @ W3(layer1)  folded classifier (20x3)
#define OFF_A1  0
#define OFF_B1  400
#define OFF_C1  800
#define OFF_D1  1200
#define OFF_A2  1600
#define OFF_B2  2000
#define OFF_M2  2400
#define OFF_M3  2460
#define OFF_B11 2520
#define OFF_E1  2540
#define OFF_B12 2560
#define OFF_CC  2580
// total 2583 floats = 10332 bytes of d_ws

__global__ void prep_kernel(const float* __restrict__ Wv, const float* __restrict__ Wres,
                            const float* __restrict__ W1, const float* __restrict__ b1,
                            const float* __restrict__ W2, const float* __restrict__ b2,
                            const float* __restrict__ W3, const float* __restrict__ b3,
                            const float* __restrict__ Wc, const float* __restrict__ bc,
                            float* __restrict__ W) {
    const int tid = threadIdx.x;
    const int nt  = blockDim.x;
    for (int idx = tid; idx < 400; idx += nt) {
        const int r = idx / 20, c = idx % 20;     // idx = r*20 + c
        // A_l[i=r][j=c] = Wv[l][c][r] + Wres[l][r][c]   (out_j = sum_i x_i * A[i][j])
        W[OFF_A1 + idx] = Wv[c * 20 + r] + Wres[idx];
        W[OFF_A2 + idx] = Wv[400 + c * 20 + r] + Wres[400 + idx];
        // B_l[j=r][i=c] = W1[l][c][r]   (h_i = sum_j t_j * B[j][i])
        W[OFF_B1 + idx] = W1[c * 20 + r];
        W[OFF_B2 + idx] = W1[400 + c * 20 + r];
        // C1[j=r][i=c] = W2[0][c][r]
        W[OFF_C1 + idx] = W2[c * 20 + r];
        // D1[j=r][i=c] = W3[0][c][r]
        W[OFF_D1 + idx] = W3[c * 20 + r];
    }
    for (int idx = tid; idx < 60; idx += nt) {
        const int j = idx / 3, c = idx % 3;
        float m2 = 0.f, m3 = 0.f;
        for (int i = 0; i < 20; ++i) {
            m2 = fmaf(Wc[c * 20 + i], W2[400 + i * 20 + j], m2);
            m3 = fmaf(Wc[c * 20 + i], W3[400 + i * 20 + j], m3);
        }
        W[OFF_M2 + idx] = m2;
        W[OFF_M3 + idx] = m3;
    }
    for (int i = tid; i < 20; i += nt) {
        W[OFF_B11 + i] = b1[i];                // layer-0 b1
        W[OFF_E1  + i] = b2[i] + b3[i];        // layer-0 b2+b3
        W[OFF_B12 + i] = b1[20 + i];           // layer-1 b1
    }
    if (tid < 3) {
        float s = bc[tid];
        for (int i = 0; i < 20; ++i)
            s = fmaf(Wc[tid * 20 + i], b2[20 + i] + b3[20 + i], s);
        W[OFF_CC + tid] = s;
    }
}

__device__ __forceinline__ void mv20_acc(const float* __restrict__ M,
                                         const float* __restrict__ in,
                                         float* __restrict__ acc) {
    #pragma unroll
    for (int i = 0; i < 20; ++i) {
        const float xi = in[i];
        #pragma unroll
        for (int j = 0; j < 20; ++j)
            acc[j] = fmaf(xi, M[i * 20 + j], acc[j]);
    }
}

__global__ __launch_bounds__(256) void fwd_kernel(const float* __restrict__ X,
                                                  const float* __restrict__ W,
                                                  float* __restrict__ out, int S) {
    const int stride = gridDim.x * blockDim.x;
    for (int t = blockIdx.x * blockDim.x + threadIdx.x; t < S; t += stride) {
        float x[20];
        const float4* xp = reinterpret_cast<const float4*>(X + (size_t)t * DTOK);
        #pragma unroll
        for (int q = 0; q < 5; ++q) {
            const float4 v4 = xp[q];
            x[4 * q + 0] = v4.x; x[4 * q + 1] = v4.y;
            x[4 * q + 2] = v4.z; x[4 * q + 3] = v4.w;
        }

        // ---------------- layer 1 ----------------
        float tb[20];
        #pragma unroll
        for (int j = 0; j < 20; ++j) tb[j] = 0.f;
        mv20_acc(W + OFF_A1, x, tb);           // tb = x @ (Wv^T + Wres)

        float h[20];
        #pragma unroll
        for (int i = 0; i < 20; ++i) h[i] = W[OFF_B11 + i];
        mv20_acc(W + OFF_B1, tb, h);           // + tb @ W1^T
        #pragma unroll
        for (int i = 0; i < 20; ++i) h[i] = fmaxf(h[i], 0.f);

        float x1[20];
        #pragma unroll
        for (int i = 0; i < 20; ++i) x1[i] = W[OFF_E1 + i];
        mv20_acc(W + OFF_C1, h, x1);           // + h @ W2^T
        mv20_acc(W + OFF_D1, x, x1);           // + x @ W3^T

        // ------------- layer 2 (classifier-folded) -------------
        float tb2[20];
        #pragma unroll
        for (int j = 0; j < 20; ++j) tb2[j] = 0.f;
        mv20_acc(W + OFF_A2, x1, tb2);

        float h2[20];
        #pragma unroll
        for (int i = 0; i < 20; ++i) h2[i] = W[OFF_B12 + i];
        mv20_acc(W + OFF_B2, tb2, h2);
        #pragma unroll
        for (int i = 0; i < 20; ++i) h2[i] = fmaxf(h2[i], 0.f);

        float l0 = W[OFF_CC + 0], l1 = W[OFF_CC + 1], l2 = W[OFF_CC + 2];
        #pragma unroll
        for (int j = 0; j < 20; ++j) {
            l0 = fmaf(h2[j], W[OFF_M2 + j * 3 + 0], l0);
            l1 = fmaf(h2[j], W[OFF_M2 + j * 3 + 1], l1);
            l2 = fmaf(h2[j], W[OFF_M2 + j * 3 + 2], l2);
            l0 = fmaf(x1[j], W[OFF_M3 + j * 3 + 0], l0);
            l1 = fmaf(x1[j], W[OFF_M3 + j * 3 + 1], l1);
            l2 = fmaf(x1[j], W[OFF_M3 + j * 3 + 2], l2);
        }

        const float m  = fmaxf(fmaxf(l0, l1), l2);
        const float e0 = __expf(l0 - m);
        const float e1 = __expf(l1 - m);
        const float e2 = __expf(l2 - m);
        const float r  = 1.f / (e0 + e1 + e2);
        float* o = out + (size_t)t * 3;
        o[0] = e0 * r; o[1] = e1 * r; o[2] = e2 * r;
    }
}

extern "C" void kernel_launch(void* const* d_in, const int* in_sizes, int n_in,
                              void* d_out, int out_size, void* d_ws, size_t ws_size,
                              hipStream_t stream) {
    const float* X    = (const float*)d_in[0];
    // d_in[1] = Wq, d_in[2] = Wk : dead (softmax over singleton axis == 1)
    const float* Wv   = (const float*)d_in[3];
    const float* Wres = (const float*)d_in[4];
    const float* W1   = (const float*)d_in[5];
    const float* b1   = (const float*)d_in[6];
    const float* W2   = (const float*)d_in[7];
    const float* b2   = (const float*)d_in[8];
    const float* W3   = (const float*)d_in[9];
    const float* b3   = (const float*)d_in[10];
    const float* Wc   = (const float*)d_in[11];
    const float* bc   = (const float*)d_in[12];
    float* out = (float*)d_out;
    float* W   = (float*)d_ws;

    const int S = in_sizes[0] / DTOK;

    prep_kernel<<<1, 256, 0, stream>>>(Wv, Wres, W1, b1, W2, b2, W3, b3, Wc, bc, W);

    const int block = 256;
    int grid = (S + block - 1) / block;
    fwd_kernel<<<grid, block, 0, stream>>>(X, W, out, S);
}

// Round 2
// 176.338 us; speedup vs baseline: 2.2057x; 2.2057x over previous
//
#include <hip/hip_runtime.h>
#include <math.h>

// Folded model (exact algebra, per-token):
//   h      = relu(x @ G1 + b11)                      [400 MACs]
//   h2     = relu(h @ P1 + x @ P2 + f2)              [800 MACs]
//   logits = h2 @ M2 + h @ Q1 + x @ Q2 + f3          [180 MACs]
//   out    = softmax(logits)
// where (layer arrays l=0 at offset 0, l=1 at offset 400):
//   A_l[i][j] = Wv_l[j][i] + Wres_l[i][j]
//   G_l[k][m] = sum_j A_l[k][j] * W1_l[m][j]       (A folded through W1)
//   C1[m'][i] = W2_0[i][m'] ; D1[k][i] = W3_0[i][k] ; e1 = b2_0 + b3_0
//   M2[m][c]  = sum_p Wc[c][p]*W2_1[p][m] ; M3[i][c] = sum_p Wc[c][p]*W3_1[p][i]
//   P1 = C1@G2 ; P2 = D1@G2 ; Q1 = C1@M3 ; Q2 = D1@M3
//   f2 = b1_1 + e1@G2 ; f3 = bc + Wc@(b2_1+b3_1) + e1@M3

// d_ws layout (float offsets), all rows 20 floats = 80 B (16B-aligned)
#define OFF_G1   0      // [20][20] k-major
#define OFF_P1   400    // [20][20] m'-major
#define OFF_P2   800    // [20][20] k-major
#define OFF_M2   1200   // [3][20]  (M2r[c][m])
#define OFF_Q1   1260   // [3][20]  (Q1r[c][m'])
#define OFF_Q2   1320   // [3][20]  (Q2r[c][k])
#define OFF_B11  1380   // [20]
#define OFF_F2   1400   // [20]
#define OFF_F3   1420   // [3]
#define NWTOT    1423

__global__ void prep_kernel(const float* __restrict__ Wv, const float* __restrict__ Wres,
                            const float* __restrict__ W1, const float* __restrict__ b1,
                            const float* __restrict__ W2, const float* __restrict__ b2,
                            const float* __restrict__ W3, const float* __restrict__ b3,
                            const float* __restrict__ Wc, const float* __restrict__ bc,
                            float* __restrict__ W) {
    __shared__ float G2[400];   // [i][m]
    __shared__ float M3[60];    // [i][c]
    __shared__ float e1[20];
    const int tid = threadIdx.x;
    // ---- phase A: layer-1 folds ----
    for (int idx = tid; idx < 480; idx += 256) {
        if (idx < 400) {
            const int i = idx / 20, m = idx % 20;
            float s = 0.f;
            for (int j = 0; j < 20; ++j)
                s = fmaf(Wv[400 + j*20 + i] + Wres[400 + i*20 + j], W1[400 + m*20 + j], s);
            G2[idx] = s;
        } else if (idx < 460) {
            const int r = idx - 400, i = r / 3, c = r % 3;
            float s = 0.f;
            for (int p = 0; p < 20; ++p)
                s = fmaf(Wc[c*20 + p], W3[400 + p*20 + i], s);
            M3[r] = s;
        } else {
            const int j = idx - 460;
            e1[j] = b2[j] + b3[j];
        }
    }
    __syncthreads();
    // ---- phase B: final folded weights → d_ws ----
    for (int idx = tid; idx < NWTOT; idx += 256) {
        float s = 0.f;
        if (idx < 400) {                       // G1[k][m]
            const int k = idx / 20, m = idx % 20;
            for (int j = 0; j < 20; ++j)
                s = fmaf(Wv[j*20 + k] + Wres[k*20 + j], W1[m*20 + j], s);
        } else if (idx < 800) {                // P1[m'][m]
            const int r = idx - 400, mp = r / 20, m = r % 20;
            for (int i = 0; i < 20; ++i)
                s = fmaf(W2[i*20 + mp], G2[i*20 + m], s);
        } else if (idx < 1200) {               // P2[k][m]
            const int r = idx - 800, k = r / 20, m = r % 20;
            for (int i = 0; i < 20; ++i)
                s = fmaf(W3[i*20 + k], G2[i*20 + m], s);
        } else if (idx < 1260) {               // M2r[c][m]
            const int r = idx - 1200, c = r / 20, m = r % 20;
            for (int p = 0; p < 20; ++p)
                s = fmaf(Wc[c*20 + p], W2[400 + p*20 + m], s);
        } else if (idx < 1320) {               // Q1r[c][m']
            const int r = idx - 1260, c = r / 20, mp = r % 20;
            for (int i = 0; i < 20; ++i)
                s = fmaf(W2[i*20 + mp], M3[i*3 + c], s);
        } else if (idx < 1380) {               // Q2r[c][k]
            const int r = idx - 1320, c = r / 20, k = r % 20;
            for (int i = 0; i < 20; ++i)
                s = fmaf(W3[i*20 + k], M3[i*3 + c], s);
        } else if (idx < 1400) {               // b11
            s = b1[idx - 1380];
        } else if (idx < 1420) {               // f2
            const int m = idx - 1400;
            s = b1[20 + m];
            for (int i = 0; i < 20; ++i)
                s = fmaf(e1[i], G2[i*20 + m], s);
        } else {                               // f3
            const int c = idx - 1420;
            s = bc[c];
            for (int p = 0; p < 20; ++p)
                s = fmaf(Wc[c*20 + p], b2[20 + p] + b3[20 + p], s);
            for (int i = 0; i < 20; ++i)
                s = fmaf(e1[i], M3[i*3 + c], s);
        }
        W[idx] = s;
    }
}

// T=2 token blocking: each thread computes two consecutive tokens so every
// broadcast LDS weight read feeds 2 FMAs. Weights live in LDS (7.6 KB),
// read as ds_read_b128 broadcasts (uniform addr = conflict-free).
__global__ __launch_bounds__(256, 3) void fwd_kernel(const float* __restrict__ X,
                                                     const float* __restrict__ Wg,
                                                     float* __restrict__ out, int npair) {
    __shared__ float Ws[NWTOT + 1];
    for (int i = threadIdx.x; i < NWTOT; i += 256) Ws[i] = Wg[i];
    __syncthreads();

    const int pair = blockIdx.x * blockDim.x + threadIdx.x;
    if (pair >= npair) return;

    const float4* Wv4 = reinterpret_cast<const float4*>(Ws);

    // load 2 tokens (40 consecutive floats)
    float xa[20], xb[20];
    const float4* xp = reinterpret_cast<const float4*>(X + (size_t)pair * 40);
    #pragma unroll
    for (int q = 0; q < 5; ++q) {
        const float4 v = xp[q];
        xa[4*q+0] = v.x; xa[4*q+1] = v.y; xa[4*q+2] = v.z; xa[4*q+3] = v.w;
    }
    #pragma unroll
    for (int q = 0; q < 5; ++q) {
        const float4 v = xp[5 + q];
        xb[4*q+0] = v.x; xb[4*q+1] = v.y; xb[4*q+2] = v.z; xb[4*q+3] = v.w;
    }

    // h = relu(x @ G1 + b11)
    float ha[20], hb[20];
    #pragma unroll
    for (int q = 0; q < 5; ++q) {
        const float4 b = Wv4[OFF_B11/4 + q];
        ha[4*q+0] = b.x; ha[4*q+1] = b.y; ha[4*q+2] = b.z; ha[4*q+3] = b.w;
        hb[4*q+0] = b.x; hb[4*q+1] = b.y; hb[4*q+2] = b.z; hb[4*q+3] = b.w;
    }
    #pragma unroll
    for (int k = 0; k < 20; ++k) {
        const float x0 = xa[k], x1 = xb[k];
        #pragma unroll
        for (int q = 0; q < 5; ++q) {
            const float4 w = Wv4[OFF_G1/4 + k*5 + q];
            ha[4*q+0] = fmaf(x0, w.x, ha[4*q+0]); hb[4*q+0] = fmaf(x1, w.x, hb[4*q+0]);
            ha[4*q+1] = fmaf(x0, w.y, ha[4*q+1]); hb[4*q+1] = fmaf(x1, w.y, hb[4*q+1]);
            ha[4*q+2] = fmaf(x0, w.z, ha[4*q+2]); hb[4*q+2] = fmaf(x1, w.z, hb[4*q+2]);
            ha[4*q+3] = fmaf(x0, w.w, ha[4*q+3]); hb[4*q+3] = fmaf(x1, w.w, hb[4*q+3]);
        }
    }
    #pragma unroll
    for (int i = 0; i < 20; ++i) { ha[i] = fmaxf(ha[i], 0.f); hb[i] = fmaxf(hb[i], 0.f); }

    // g = relu(h @ P1 + x @ P2 + f2)
    float ga[20], gb[20];
    #pragma unroll
    for (int q = 0; q < 5; ++q) {
        const float4 b = Wv4[OFF_F2/4 + q];
        ga[4*q+0] = b.x; ga[4*q+1] = b.y; ga[4*q+2] = b.z; ga[4*q+3] = b.w;
        gb[4*q+0] = b.x; gb[4*q+1] = b.y; gb[4*q+2] = b.z; gb[4*q+3] = b.w;
    }
    #pragma unroll
    for (int k = 0; k < 20; ++k) {
        const float h0 = ha[k], h1 = hb[k];
        #pragma unroll
        for (int q = 0; q < 5; ++q) {
            const float4 w = Wv4[OFF_P1/4 + k*5 + q];
            ga[4*q+0] = fmaf(h0, w.x, ga[4*q+0]); gb[4*q+0] = fmaf(h1, w.x, gb[4*q+0]);
            ga[4*q+1] = fmaf(h0, w.y, ga[4*q+1]); gb[4*q+1] = fmaf(h1, w.y, gb[4*q+1]);
            ga[4*q+2] = fmaf(h0, w.z, ga[4*q+2]); gb[4*q+2] = fmaf(h1, w.z, gb[4*q+2]);
            ga[4*q+3] = fmaf(h0, w.w, ga[4*q+3]); gb[4*q+3] = fmaf(h1, w.w, gb[4*q+3]);
        }
        const float x0 = xa[k], x1 = xb[k];
        #pragma unroll
        for (int q = 0; q < 5; ++q) {
            const float4 w = Wv4[OFF_P2/4 + k*5 + q];
            ga[4*q+0] = fmaf(x0, w.x, ga[4*q+0]); gb[4*q+0] = fmaf(x1, w.x, gb[4*q+0]);
            ga[4*q+1] = fmaf(x0, w.y, ga[4*q+1]); gb[4*q+1] = fmaf(x1, w.y, gb[4*q+1]);
            ga[4*q+2] = fmaf(x0, w.z, ga[4*q+2]); gb[4*q+2] = fmaf(x1, w.z, gb[4*q+2]);
            ga[4*q+3] = fmaf(x0, w.w, ga[4*q+3]); gb[4*q+3] = fmaf(x1, w.w, gb[4*q+3]);
        }
    }
    #pragma unroll
    for (int i = 0; i < 20; ++i) { ga[i] = fmaxf(ga[i], 0.f); gb[i] = fmaxf(gb[i], 0.f); }

    // logits = g @ M2 + h @ Q1 + x @ Q2 + f3
    float la[3], lb[3];
    #pragma unroll
    for (int c = 0; c < 3; ++c) {
        float sa = Ws[OFF_F3 + c];
        float sb = sa;
        #pragma unroll
        for (int q = 0; q < 5; ++q) {
            const float4 wm = Wv4[OFF_M2/4 + c*5 + q];
            const float4 wq1 = Wv4[OFF_Q1/4 + c*5 + q];
            const float4 wq2 = Wv4[OFF_Q2/4 + c*5 + q];
            sa = fmaf(ga[4*q+0], wm.x, sa);  sb = fmaf(gb[4*q+0], wm.x, sb);
            sa = fmaf(ga[4*q+1], wm.y, sa);  sb = fmaf(gb[4*q+1], wm.y, sb);
            sa = fmaf(ga[4*q+2], wm.z, sa);  sb = fmaf(gb[4*q+2], wm.z, sb);
            sa = fmaf(ga[4*q+3], wm.w, sa);  sb = fmaf(gb[4*q+3], wm.w, sb);
            sa = fmaf(ha[4*q+0], wq1.x, sa); sb = fmaf(hb[4*q+0], wq1.x, sb);
            sa = fmaf(ha[4*q+1], wq1.y, sa); sb = fmaf(hb[4*q+1], wq1.y, sb);
            sa = fmaf(ha[4*q+2], wq1.z, sa); sb = fmaf(hb[4*q+2], wq1.z, sb);
            sa = fmaf(ha[4*q+3], wq1.w, sa); sb = fmaf(hb[4*q+3], wq1.w, sb);
            sa = fmaf(xa[4*q+0], wq2.x, sa); sb = fmaf(xb[4*q+0], wq2.x, sb);
            sa = fmaf(xa[4*q+1], wq2.y, sa); sb = fmaf(xb[4*q+1], wq2.y, sb);
            sa = fmaf(xa[4*q+2], wq2.z, sa); sb = fmaf(xb[4*q+2], wq2.z, sb);
            sa = fmaf(xa[4*q+3], wq2.w, sa); sb = fmaf(xb[4*q+3], wq2.w, sb);
        }
        la[c] = sa; lb[c] = sb;
    }

    // softmax + store (2 tokens × 3 probs = 6 consecutive floats, 8B aligned)
    const float ma = fmaxf(fmaxf(la[0], la[1]), la[2]);
    const float ea0 = __expf(la[0] - ma), ea1 = __expf(la[1] - ma), ea2 = __expf(la[2] - ma);
    const float ra = 1.f / (ea0 + ea1 + ea2);
    const float mb = fmaxf(fmaxf(lb[0], lb[1]), lb[2]);
    const float eb0 = __expf(lb[0] - mb), eb1 = __expf(lb[1] - mb), eb2 = __expf(lb[2] - mb);
    const float rb = 1.f / (eb0 + eb1 + eb2);

    float2* o2 = reinterpret_cast<float2*>(out + (size_t)pair * 6);
    o2[0] = make_float2(ea0 * ra, ea1 * ra);
    o2[1] = make_float2(ea2 * ra, eb0 * rb);
    o2[2] = make_float2(eb1 * rb, eb2 * rb);
}

extern "C" void kernel_launch(void* const* d_in, const int* in_sizes, int n_in,
                              void* d_out, int out_size, void* d_ws, size_t ws_size,
                              hipStream_t stream) {
    const float* X    = (const float*)d_in[0];
    // d_in[1]=Wq, d_in[2]=Wk: dead (softmax over singleton axis == 1)
    const float* Wv   = (const float*)d_in[3];
    const float* Wres = (const float*)d_in[4];
    const float* W1   = (const float*)d_in[5];
    const float* b1   = (const float*)d_in[6];
    const float* W2   = (const float*)d_in[7];
    const float* b2   = (const float*)d_in[8];
    const float* W3   = (const float*)d_in[9];
    const float* b3   = (const float*)d_in[10];
    const float* Wc   = (const float*)d_in[11];
    const float* bc   = (const float*)d_in[12];
    float* out = (float*)d_out;
    float* W   = (float*)d_ws;

    const int S = in_sizes[0] / 20;
    const int npair = S / 2;   // S = 1048576 divides evenly

    prep_kernel<<<1, 256, 0, stream>>>(Wv, Wres, W1, b1, W2, b2, W3, b3, Wc, bc, W);

    const int block = 256;
    const int grid = (npair + block - 1) / block;
    fwd_kernel<<<grid, block, 0, stream>>>(X, W, out, npair);
}